// Round 6
// baseline (443.918 us; speedup 1.0000x reference)
//
#include <hip/hip_runtime.h>
#include <hip/hip_bf16.h>
#include <math.h>

#define K_ 4
#define B_ 64
#define S_ 50
#define D_ 256
#define V_ 40000
#define H_ 4
#define DH_ 64
#define NEG_ (-1e9f)
#define SCALE_ 0.125f

typedef __attribute__((ext_vector_type(8))) __bf16 bf16x8v;
typedef __attribute__((ext_vector_type(4))) float f32x4v;

// ---------- helpers ----------
__device__ __forceinline__ float wred_sum(float v) {
#pragma unroll
  for (int off = 32; off > 0; off >>= 1) v += __shfl_xor(v, off, 64);
  return v;
}
__device__ __forceinline__ float wred_max(float v) {
#pragma unroll
  for (int off = 32; off > 0; off >>= 1) v = fmaxf(v, __shfl_xor(v, off, 64));
  return v;
}
__device__ __forceinline__ float softplusf(float x) {
  return (x > 20.f) ? x : log1pf(expf(x));
}
__device__ __forceinline__ float geluf(float x) {
  const float c = 0.7978845608028654f;  // sqrt(2/pi)
  float x3 = x * x * x;
  return 0.5f * x * (1.f + tanhf(c * (x + 0.044715f * x3)));
}
__device__ __forceinline__ unsigned short f2bf(float f) {
  unsigned u = __float_as_uint(f);
  return (unsigned short)((u + 0x7fffu + ((u >> 16) & 1u)) >> 16);
}
__device__ __forceinline__ bf16x8v cvt8(float4 a, float4 b) {
  bf16x8v r;
  r[0] = (__bf16)a.x; r[1] = (__bf16)a.y; r[2] = (__bf16)a.z; r[3] = (__bf16)a.w;
  r[4] = (__bf16)b.x; r[5] = (__bf16)b.y; r[6] = (__bf16)b.z; r[7] = (__bf16)b.w;
  return r;
}

// ---------- fused front: local_agg+gather+LN1 [0,256) | weight cast [256,1024)
// | gating [1024,1824). All three mutually independent. (unchanged, validated)
__global__ __launch_bounds__(256) void front_kernel(
    const int* __restrict__ items, const int* __restrict__ adj,
    const float* __restrict__ emb, const float* __restrict__ agg_a,
    const int* __restrict__ alias_, float* __restrict__ hbuf,
    unsigned short* __restrict__ xb,
    const float* __restrict__ ln1g, const float* __restrict__ ln1b,
    const int* __restrict__ ids, const float* __restrict__ Wg,
    const float* __restrict__ Wn, const float* __restrict__ eps,
    float* __restrict__ gates,
    const float* __restrict__ wq, const float* __restrict__ wk,
    const float* __restrict__ wv, const float* __restrict__ wo,
    const float* __restrict__ w1, const float* __restrict__ w2,
    unsigned short* __restrict__ wqkvT, unsigned short* __restrict__ woT,
    unsigned short* __restrict__ w1T, unsigned short* __restrict__ w2T) {
  __shared__ __align__(16) char smem[62816];
  int bid = blockIdx.x;
  int t = threadIdx.x;

  if (bid < 256) {
    typedef __bf16 (*arr264)[264];
    arr264 hgb = (arr264)smem;
    float (*e_f)[68] = (float(*)[68])(smem + 33792);
    unsigned char (*adj_s)[64] = (unsigned char(*)[64])(smem + 47392);
    arr264 a_sb = (arr264)(smem + 51488);
    __bf16 (*alp)[72] = (__bf16(*)[72])(smem + 53600);
    float* hl = (float*)smem;  // [50][260] overlay, used after PV

    int kb = bid;
    int k = kb >> 6, b = kb & 63;
    for (int c = t; c < 2048; c += 256) {
      int row = c >> 5, c8 = (c & 31) * 8;
      bf16x8v val;
      if (row < S_) {
        int g = items[kb * S_ + row];
        const float* src = emb + ((long)k * V_ + g) * D_ + c8;
        val = cvt8(*(const float4*)src, *(const float4*)(src + 4));
      } else {
#pragma unroll
        for (int e = 0; e < 8; ++e) val[e] = (__bf16)0.f;
      }
      *(bf16x8v*)&hgb[row][c8] = val;
    }
    if (t < 128) {
      int row = t >> 5, c8 = (t & 31) * 8;
      const float* src = agg_a + ((long)k * 4 + row) * D_ + c8;
      *(bf16x8v*)&a_sb[row][c8] = cvt8(*(const float4*)src, *(const float4*)(src + 4));
    }
    for (int c = t; c < 4096; c += 256) {
      int i = c >> 6, j = c & 63;
      adj_s[i][j] = (i < S_ && j < S_)
                        ? (unsigned char)adj[((long)b * S_ + i) * S_ + j] : 0;
    }
    __syncthreads();
    int w = t >> 6, lane = t & 63;
    int m16 = lane & 15, quad = lane >> 4;
    float e_sel[4][4];
#pragma unroll
    for (int nt = 0; nt < 4; ++nt)
#pragma unroll
      for (int rg = 0; rg < 4; ++rg) e_sel[nt][rg] = NEG_;
#pragma unroll
    for (int r = 0; r < 4; ++r) {
      f32x4v acc[4];
#pragma unroll
      for (int nt = 0; nt < 4; ++nt) acc[nt] = (f32x4v){0.f, 0.f, 0.f, 0.f};
#pragma unroll
      for (int k0 = 0; k0 < 8; ++k0) {
        int kc = k0 * 32 + quad * 8;
        bf16x8v hr = *(const bf16x8v*)&hgb[w * 16 + m16][kc];
        bf16x8v ar = *(const bf16x8v*)&a_sb[r][kc];
        bf16x8v af;
#pragma unroll
        for (int e = 0; e < 8; ++e) af[e] = (__bf16)((float)hr[e] * (float)ar[e]);
#pragma unroll
        for (int nt = 0; nt < 4; ++nt) {
          bf16x8v bf = *(const bf16x8v*)&hgb[nt * 16 + m16][kc];
          acc[nt] = __builtin_amdgcn_mfma_f32_16x16x32_bf16(af, bf, acc[nt], 0, 0, 0);
        }
      }
#pragma unroll
      for (int nt = 0; nt < 4; ++nt)
#pragma unroll
        for (int rg = 0; rg < 4; ++rg) {
          int i = w * 16 + quad * 4 + rg, j = nt * 16 + m16;
          if (adj_s[i][j] == r + 1) {
            float v = acc[nt][rg];
            e_sel[nt][rg] = (v >= 0.f) ? v : 0.2f * v;
          }
        }
    }
#pragma unroll
    for (int nt = 0; nt < 4; ++nt)
#pragma unroll
      for (int rg = 0; rg < 4; ++rg) {
        int i = w * 16 + quad * 4 + rg;
        if (i < S_) e_f[i][nt * 16 + m16] = e_sel[nt][rg];
      }
    __syncthreads();
    for (int i = w; i < S_; i += 4) {
      float val = (lane < S_) ? e_f[i][lane] : -INFINITY;
      float m = wred_max(val);
      float p = expf(val - m);
      float ssum = wred_sum(p);
      alp[i][lane] = (__bf16)(p / ssum);
    }
    __syncthreads();
    f32x4v acc16[16];
#pragma unroll
    for (int nt = 0; nt < 16; ++nt) {
      f32x4v acc = (f32x4v){0.f, 0.f, 0.f, 0.f};
#pragma unroll
      for (int k0 = 0; k0 < 2; ++k0) {
        int jb = k0 * 32 + quad * 8;
        bf16x8v af = *(const bf16x8v*)&alp[w * 16 + m16][jb];
        bf16x8v bf;
#pragma unroll
        for (int tt = 0; tt < 8; ++tt) bf[tt] = hgb[jb + tt][nt * 16 + m16];
        acc = __builtin_amdgcn_mfma_f32_16x16x32_bf16(af, bf, acc, 0, 0, 0);
      }
      acc16[nt] = acc;
    }
    __syncthreads();
#pragma unroll
    for (int nt = 0; nt < 16; ++nt)
#pragma unroll
      for (int rg = 0; rg < 4; ++rg) {
        int i = w * 16 + quad * 4 + rg;
        if (i < S_) hl[i * 260 + nt * 16 + m16] = acc16[nt][rg];
      }
    __syncthreads();
    for (int s = w; s < S_; s += 4) {
      int src = alias_[b * S_ + s];
      const float4 v = *(const float4*)&hl[src * 260 + lane * 4];
      long off = ((long)kb * S_ + s) * D_ + lane * 4;
      *(float4*)(hbuf + off) = v;
      float sum = wred_sum(v.x + v.y + v.z + v.w);
      float sq = wred_sum(v.x * v.x + v.y * v.y + v.z * v.z + v.w * v.w);
      float mean = sum * (1.f / D_);
      float var = sq * (1.f / D_) - mean * mean;
      float rs = rsqrtf(var + 1e-5f);
      const float4 gv = *(const float4*)(ln1g + k * D_ + lane * 4);
      const float4 bv = *(const float4*)(ln1b + k * D_ + lane * 4);
      ushort4 o;
      o.x = f2bf((v.x - mean) * rs * gv.x + bv.x);
      o.y = f2bf((v.y - mean) * rs * gv.y + bv.y);
      o.z = f2bf((v.z - mean) * rs * gv.z + bv.z);
      o.w = f2bf((v.w - mean) * rs * gv.w + bv.w);
      *(ushort4*)(xb + off) = o;
    }
    return;
  }

  if (bid < 1024) {
    int tid = bid - 256;
    typedef unsigned short row66[66];
    row66* tile = (row66*)smem;
    const float* src; unsigned short* dst; int C, R; int r0, c0;
    if (tid < 192) {
      int sect = tid >> 6; int rem = tid & 63;
      int k = rem >> 4, t2 = rem & 15;
      r0 = (t2 >> 2) * 64; c0 = (t2 & 3) * 64;
      src = ((sect == 0) ? wq : (sect == 1) ? wk : wv) + (long)k * 65536;
      dst = wqkvT + ((long)k * 768 + sect * 256) * 256;
      R = 256; C = 256;
    } else if (tid < 256) {
      int rem = tid - 192; int k = rem >> 4, t2 = rem & 15;
      r0 = (t2 >> 2) * 64; c0 = (t2 & 3) * 64;
      src = wo + (long)k * 65536; dst = woT + (long)k * 65536;
      R = 256; C = 256;
    } else if (tid < 512) {
      int rem = tid - 256; int k = rem >> 6, t2 = rem & 63;
      r0 = (t2 >> 4) * 64; c0 = (t2 & 15) * 64;
      src = w1 + (long)k * 262144; dst = w1T + (long)k * 262144;
      R = 256; C = 1024;
    } else {
      int rem = tid - 512; int k = rem >> 6, t2 = rem & 63;
      r0 = (t2 >> 2) * 64; c0 = (t2 & 3) * 64;
      src = w2 + (long)k * 262144; dst = w2T + (long)k * 262144;
      R = 1024; C = 256;
    }
    int sr = t >> 2, sc = (t & 3) * 16;
    const float* p = src + (long)(r0 + sr) * C + c0 + sc;
#pragma unroll
    for (int q = 0; q < 4; ++q) {
      float4 f = *(const float4*)(p + q * 4);
      tile[sr][sc + q * 4 + 0] = f2bf(f.x);
      tile[sr][sc + q * 4 + 1] = f2bf(f.y);
      tile[sr][sc + q * 4 + 2] = f2bf(f.z);
      tile[sr][sc + q * 4 + 3] = f2bf(f.w);
    }
    __syncthreads();
    int dc = t >> 2, ch = (t & 3) * 16;
    unsigned int wds[8];
#pragma unroll
    for (int i = 0; i < 8; ++i)
      wds[i] = (unsigned int)tile[ch + 2 * i][dc] |
               ((unsigned int)tile[ch + 2 * i + 1][dc] << 16);
    unsigned short* dp = dst + (long)(c0 + dc) * R + r0 + ch;
    uint4 o0 = make_uint4(wds[0], wds[1], wds[2], wds[3]);
    uint4 o1 = make_uint4(wds[4], wds[5], wds[6], wds[7]);
    *(uint4*)dp = o0;
    *(uint4*)(dp + 8) = o1;
    return;
  }

  {
    int w = t >> 6, lane = t & 63;
    int item = (bid - 1024) * 4 + w;
    int b = item / S_, s = item % S_;
    int d0 = lane * 4;
    float4 hs = make_float4(0.f, 0.f, 0.f, 0.f);
#pragma unroll
    for (int k = 0; k < K_; ++k) {
      int id = ids[(k * B_ + b) * S_ + s];
      const float4 e = *(const float4*)(emb + ((long)k * V_ + id) * D_ + d0);
      hs.x += e.x; hs.y += e.y; hs.z += e.z; hs.w += e.w;
    }
    hs.x *= 0.25f; hs.y *= 0.25f; hs.z *= 0.25f; hs.w *= 0.25f;
    float logit[4];
#pragma unroll
    for (int j = 0; j < K_; ++j) {
      float pg = hs.x * Wg[(d0 + 0) * K_ + j] + hs.y * Wg[(d0 + 1) * K_ + j] +
                 hs.z * Wg[(d0 + 2) * K_ + j] + hs.w * Wg[(d0 + 3) * K_ + j];
      float pn = hs.x * Wn[(d0 + 0) * K_ + j] + hs.y * Wn[(d0 + 1) * K_ + j] +
                 hs.z * Wn[(d0 + 2) * K_ + j] + hs.w * Wn[(d0 + 3) * K_ + j];
      pg = wred_sum(pg);
      pn = wred_sum(pn);
      logit[j] = pg + softplusf(pn) * eps[item * K_ + j];
    }
    if (lane == 0) {
      int i0 = 0; float v0 = logit[0];
      for (int j = 1; j < K_; ++j) if (logit[j] > v0) { v0 = logit[j]; i0 = j; }
      int i1 = -1; float v1 = 0.f;
      for (int j = 0; j < K_; ++j)
        if (j != i0 && (i1 < 0 || logit[j] > v1)) { v1 = logit[j]; i1 = j; }
      float w0 = 1.f / (1.f + expf(v1 - v0));
      float w1 = 1.f - w0;
#pragma unroll
      for (int j = 0; j < K_; ++j)
        gates[item * K_ + j] = (j == i0) ? w0 : ((j == i1) ? w1 : 0.f);
    }
  }
}

// ---------- fused QKV projection + causal MHA, block per (k,b,h) ----------
// Wave w computes cols w*16..w*16+15 of the head's 64-col Q/K/V slices
// (A-fragments streamed from xb via L2, B from wqkvT), stores to LDS, then
// runs the validated attn_mfma body. o -> ob (separate buffer: xb stays x).
__global__ __launch_bounds__(256) void qkv_attn(
    const unsigned short* __restrict__ xb,
    const unsigned short* __restrict__ wqkvT,
    unsigned short* __restrict__ ob) {
  __shared__ __bf16 qs[64][72], ks[64][72], vs[64][72];
  __shared__ __bf16 psh[64][72], psl[64][72];
  int idx = blockIdx.x;
  int h = idx & 3, kb = idx >> 2;
  int k = kb >> 6;
  int t = threadIdx.x, w = t >> 6, lane = t & 63;
  int m16 = lane & 15, quad = lane >> 4;
  const unsigned short* xrow = xb + (long)kb * S_ * D_;
#pragma unroll
  for (int sect = 0; sect < 3; ++sect) {
    f32x4v acc[4];
#pragma unroll
    for (int mr = 0; mr < 4; ++mr) acc[mr] = (f32x4v){0.f, 0.f, 0.f, 0.f};
    const unsigned short* wrow =
        wqkvT + ((long)k * 768 + sect * 256 + h * 64 + w * 16 + m16) * 256;
#pragma unroll
    for (int st = 0; st < 8; ++st) {
      int kc = st * 32 + quad * 8;
      bf16x8v bf = *(const bf16x8v*)(wrow + kc);
#pragma unroll
      for (int mr = 0; mr < 4; ++mr) {
        bf16x8v af = *(const bf16x8v*)(xrow + (long)(mr * 16 + m16) * 256 + kc);
        acc[mr] = __builtin_amdgcn_mfma_f32_16x16x32_bf16(af, bf, acc[mr], 0, 0, 0);
      }
    }
    __bf16 (*dst)[72] = (sect == 0) ? qs : (sect == 1) ? ks : vs;
#pragma unroll
    for (int mr = 0; mr < 4; ++mr)
#pragma unroll
      for (int i2 = 0; i2 < 4; ++i2)
        dst[mr * 16 + quad * 4 + i2][w * 16 + m16] = (__bf16)acc[mr][i2];
  }
  __syncthreads();
  // zero V pad rows (rows>=50 are garbage from OOB x rows; 0*NaN hazard in PV)
  for (int c = t; c < 14 * 72; c += 256) vs[50 + c / 72][c % 72] = (__bf16)0.f;
  __syncthreads();
  // ---- QK^T (local 64x64)
  f32x4v sacc[4];
#pragma unroll
  for (int nt = 0; nt < 4; ++nt) sacc[nt] = (f32x4v){0.f, 0.f, 0.f, 0.f};
#pragma unroll
  for (int k0 = 0; k0 < 2; ++k0) {
    int kc = k0 * 32 + quad * 8;
    bf16x8v af = *(const bf16x8v*)&qs[w * 16 + m16][kc];
#pragma unroll
    for (int nt = 0; nt < 4; ++nt) {
      bf16x8v bf = *(const bf16x8v*)&ks[nt * 16 + m16][kc];
      sacc[nt] = __builtin_amdgcn_mfma_f32_16x16x32_bf16(af, bf, sacc[nt], 0, 0, 0);
    }
  }
  // ---- masked softmax per row (16-lane shfl stays inside the quad)
#pragma unroll
  for (int rg = 0; rg < 4; ++rg) {
    int i = w * 16 + quad * 4 + rg;
    float v4[4];
    if (i < S_) {
      float mx = -INFINITY;
#pragma unroll
      for (int nt = 0; nt < 4; ++nt) {
        int j = nt * 16 + m16;
        float vv = (j <= i) ? sacc[nt][rg] * SCALE_ : -INFINITY;
        v4[nt] = vv;
        mx = fmaxf(mx, vv);
      }
#pragma unroll
      for (int off = 1; off < 16; off <<= 1)
        mx = fmaxf(mx, __shfl_xor(mx, off, 64));
      float sum = 0.f;
#pragma unroll
      for (int nt = 0; nt < 4; ++nt) {
        v4[nt] = expf(v4[nt] - mx);
        sum += v4[nt];
      }
#pragma unroll
      for (int off = 1; off < 16; off <<= 1) sum += __shfl_xor(sum, off, 64);
      float inv = 1.f / sum;
#pragma unroll
      for (int nt = 0; nt < 4; ++nt) v4[nt] *= inv;
    } else {
#pragma unroll
      for (int nt = 0; nt < 4; ++nt) v4[nt] = 0.f;
    }
#pragma unroll
    for (int nt = 0; nt < 4; ++nt) {
      __bf16 hi = (__bf16)v4[nt];
      psh[i][nt * 16 + m16] = hi;
      psl[i][nt * 16 + m16] = (__bf16)(v4[nt] - (float)hi);
    }
  }
  __syncthreads();
  // ---- PV (hi+lo split for fp32-fidelity P)
  f32x4v oacc[4];
#pragma unroll
  for (int nt = 0; nt < 4; ++nt) oacc[nt] = (f32x4v){0.f, 0.f, 0.f, 0.f};
#pragma unroll
  for (int k0 = 0; k0 < 2; ++k0) {
    int jb = k0 * 32 + quad * 8;
    bf16x8v ah = *(const bf16x8v*)&psh[w * 16 + m16][jb];
    bf16x8v al = *(const bf16x8v*)&psl[w * 16 + m16][jb];
#pragma unroll
    for (int nt = 0; nt < 4; ++nt) {
      bf16x8v bf;
#pragma unroll
      for (int tt = 0; tt < 8; ++tt) bf[tt] = vs[jb + tt][nt * 16 + m16];
      oacc[nt] = __builtin_amdgcn_mfma_f32_16x16x32_bf16(ah, bf, oacc[nt], 0, 0, 0);
      oacc[nt] = __builtin_amdgcn_mfma_f32_16x16x32_bf16(al, bf, oacc[nt], 0, 0, 0);
    }
  }
#pragma unroll
  for (int nt = 0; nt < 4; ++nt)
#pragma unroll
    for (int rg = 0; rg < 4; ++rg) {
      int i = w * 16 + quad * 4 + rg;
      if (i < S_)
        ob[((long)kb * S_ + i) * D_ + h * DH_ + nt * 16 + m16] = f2bf(oacc[nt][rg]);
    }
}

// ---------- fused tail: O-proj + residual + LN2 + FFN1 + FFN2 + gated combine
// Block per (k,b); wave w owns output cols [w*64,(w+1)*64). y and t live in
// LDS only; updated h kept in registers; weights streamed from L2.
__global__ __launch_bounds__(256) void tail_fused(
    const unsigned short* __restrict__ ob, const unsigned short* __restrict__ woT,
    const unsigned short* __restrict__ w1T, const unsigned short* __restrict__ w2T,
    const float* __restrict__ hbuf, const float* __restrict__ gates,
    const float* __restrict__ g2, const float* __restrict__ b2,
    float* __restrict__ out) {
  __shared__ __bf16 ybuf[64][264];   // 33792 B (16B-aligned rows, 2-way-free)
  __shared__ __bf16 ts[64][136];     // 17408 B (one 128-col FFN1 chunk)
  __shared__ float lnS[4][64], lnQ[4][64];
  int kb = blockIdx.x;
  int k = kb >> 6, b = kb & 63;
  int t = threadIdx.x, w = t >> 6, lane = t & 63;
  int m16 = lane & 15, quad = lane >> 4;
  // zero y pad rows once (rows >= 50 feed FFN1 A-fragments for row-tile 3)
  for (int c = t; c < 14 * 264; c += 256) ybuf[50 + c / 264][c % 264] = (__bf16)0.f;
  // ---- O-projection, v = o @ Wo
  f32x4v v[4][4];
#pragma unroll
  for (int mr = 0; mr < 4; ++mr)
#pragma unroll
    for (int nt = 0; nt < 4; ++nt) v[mr][nt] = (f32x4v){0.f, 0.f, 0.f, 0.f};
  const unsigned short* orow = ob + (long)kb * S_ * D_;
#pragma unroll
  for (int st = 0; st < 8; ++st) {
    int kc = st * 32 + quad * 8;
    bf16x8v bfv[4];
#pragma unroll
    for (int nt = 0; nt < 4; ++nt)
      bfv[nt] = *(const bf16x8v*)(woT + ((long)k * 256 + w * 64 + nt * 16 + m16) * 256 + kc);
#pragma unroll
    for (int mr = 0; mr < 4; ++mr) {
      bf16x8v af = *(const bf16x8v*)(orow + (long)(mr * 16 + m16) * 256 + kc);
#pragma unroll
      for (int nt = 0; nt < 4; ++nt)
        v[mr][nt] = __builtin_amdgcn_mfma_f32_16x16x32_bf16(af, bfv[nt], v[mr][nt], 0, 0, 0);
    }
  }
  // ---- residual + per-row partial LN stats (wave covers 64 cols)
  long hb = (long)kb * S_ * D_;
#pragma unroll
  for (int mr = 0; mr < 4; ++mr)
#pragma unroll
    for (int i2 = 0; i2 < 4; ++i2) {
      int row = mr * 16 + quad * 4 + i2;
      float s = 0.f, q = 0.f;
#pragma unroll
      for (int nt = 0; nt < 4; ++nt) {
        int col = w * 64 + nt * 16 + m16;
        float hv = (row < S_) ? hbuf[hb + (long)row * 256 + col] : 0.f;
        float vv = v[mr][nt][i2] + hv;
        v[mr][nt][i2] = vv;
        s += vv; q += vv * vv;
      }
#pragma unroll
      for (int off = 1; off < 16; off <<= 1) {
        s += __shfl_xor(s, off, 64);
        q += __shfl_xor(q, off, 64);
      }
      if (m16 == 0) { lnS[w][row] = s; lnQ[w][row] = q; }
    }
  __syncthreads();
  // ---- finalize LN2, write y (bf16, LDS)
  float gv[4], bvv[4];
#pragma unroll
  for (int nt = 0; nt < 4; ++nt) {
    int col = w * 64 + nt * 16 + m16;
    gv[nt] = g2[k * D_ + col];
    bvv[nt] = b2[k * D_ + col];
  }
#pragma unroll
  for (int mr = 0; mr < 4; ++mr)
#pragma unroll
    for (int i2 = 0; i2 < 4; ++i2) {
      int row = mr * 16 + quad * 4 + i2;
      if (row < S_) {
        float s = lnS[0][row] + lnS[1][row] + lnS[2][row] + lnS[3][row];
        float q = lnQ[0][row] + lnQ[1][row] + lnQ[2][row] + lnQ[3][row];
        float mean = s * (1.f / D_);
        float var = q * (1.f / D_) - mean * mean;
        float rs = rsqrtf(var + 1e-5f);
#pragma unroll
        for (int nt = 0; nt < 4; ++nt)
          ybuf[row][w * 64 + nt * 16 + m16] =
              (__bf16)((v[mr][nt][i2] - mean) * rs * gv[nt] + bvv[nt]);
      }
    }
  __syncthreads();
  // ---- FFN: 8 chunks of 128 hidden cols; FFN2 accumulates across chunks
  f32x4v racc[4][4];
#pragma unroll
  for (int mr = 0; mr < 4; ++mr)
#pragma unroll
    for (int nt = 0; nt < 4; ++nt) racc[mr][nt] = (f32x4v){0.f, 0.f, 0.f, 0.f};
  for (int c = 0; c < 8; ++c) {
    // FFN1: wave computes 32 t-cols of this chunk (K=256 from y)
    f32x4v a1[4][2];
#pragma unroll
    for (int mr = 0; mr < 4; ++mr)
#pragma unroll
      for (int ct = 0; ct < 2; ++ct) a1[mr][ct] = (f32x4v){0.f, 0.f, 0.f, 0.f};
#pragma unroll
    for (int st = 0; st < 8; ++st) {
      int kc = st * 32 + quad * 8;
      bf16x8v bf1[2];
#pragma unroll
      for (int ct = 0; ct < 2; ++ct) {
        int n = c * 128 + w * 32 + ct * 16 + m16;
        bf1[ct] = *(const bf16x8v*)(w1T + ((long)k * 1024 + n) * 256 + kc);
      }
#pragma unroll
      for (int mr = 0; mr < 4; ++mr) {
        bf16x8v af = *(const bf16x8v*)&ybuf[mr * 16 + m16][kc];
#pragma unroll
        for (int ct = 0; ct < 2; ++ct)
          a1[mr][ct] = __builtin_amdgcn_mfma_f32_16x16x32_bf16(af, bf1[ct], a1[mr][ct], 0, 0, 0);
      }
    }
    __syncthreads();  // previous chunk's ts reads complete
#pragma unroll
    for (int mr = 0; mr < 4; ++mr)
#pragma unroll
      for (int ct = 0; ct < 2; ++ct)
#pragma unroll
        for (int i2 = 0; i2 < 4; ++i2)
          ts[mr * 16 + quad * 4 + i2][w * 32 + ct * 16 + m16] =
              (__bf16)geluf(a1[mr][ct][i2]);
    __syncthreads();
    // FFN2 partial over this chunk's 128 K (kglob order = c*128 + ks*32 + ..)
#pragma unroll
    for (int ks = 0; ks < 4; ++ks) {
      int kc = ks * 32 + quad * 8;
      bf16x8v bf2[4];
#pragma unroll
      for (int nt = 0; nt < 4; ++nt) {
        int n = w * 64 + nt * 16 + m16;
        bf2[nt] = *(const bf16x8v*)(w2T + ((long)k * 256 + n) * 1024 + c * 128 + kc);
      }
#pragma unroll
      for (int mr = 0; mr < 4; ++mr) {
        bf16x8v af = *(const bf16x8v*)&ts[mr * 16 + m16][kc];
#pragma unroll
        for (int nt = 0; nt < 4; ++nt)
          racc[mr][nt] = __builtin_amdgcn_mfma_f32_16x16x32_bf16(af, bf2[nt], racc[mr][nt], 0, 0, 0);
      }
    }
  }
  // ---- epilogue: out += gate * (ffn2 + h); h lives in v (registers)
#pragma unroll
  for (int mr = 0; mr < 4; ++mr)
#pragma unroll
    for (int i2 = 0; i2 < 4; ++i2) {
      int row = mr * 16 + quad * 4 + i2;
      if (row < S_) {
        float gz = gates[(b * S_ + row) * 4 + k];
        if (gz != 0.f) {
#pragma unroll
          for (int nt = 0; nt < 4; ++nt) {
            long off = (long)(b * S_ + row) * 256 + w * 64 + nt * 16 + m16;
            atomicAdd(&out[off], gz * (racc[mr][nt][i2] + v[mr][nt][i2]));
          }
        }
      }
    }
}

extern "C" void kernel_launch(void* const* d_in, const int* in_sizes, int n_in,
                              void* d_out, int out_size, void* d_ws,
                              size_t ws_size, hipStream_t stream) {
  const int* ids = (const int*)d_in[0];
  const int* items = (const int*)d_in[1];
  const int* adj = (const int*)d_in[2];
  const int* alias = (const int*)d_in[3];
  const float* eps = (const float*)d_in[4];
  const float* emb = (const float*)d_in[5];
  const float* agg_a = (const float*)d_in[6];
  const float* Wq = (const float*)d_in[7];
  const float* Wk = (const float*)d_in[8];
  const float* Wv = (const float*)d_in[9];
  const float* Wo = (const float*)d_in[10];
  const float* ln1g = (const float*)d_in[11];
  const float* ln1b = (const float*)d_in[12];
  const float* W1 = (const float*)d_in[13];
  const float* W2 = (const float*)d_in[14];
  const float* ln2g = (const float*)d_in[15];
  const float* ln2b = (const float*)d_in[16];
  const float* Wg = (const float*)d_in[17];
  const float* Wn = (const float*)d_in[18];
  float* out = (float*)d_out;

  const long BSD = (long)B_ * S_ * D_;  // 819200
  float* ws = (float*)d_ws;
  float* gates = ws;                    // 16384 fp32
  float* hbuf = ws + 16384;             // [K,B,S,D] fp32 residual stream
  unsigned short* ub = (unsigned short*)(ws + 16384 + 4 * BSD);
  unsigned short* xb = ub;              // x (LN1 out) [K,B,S,D] bf16
  unsigned short* obuf = ub + 3276800;  // attn output [K,B,S,D] bf16
  unsigned short* wqkvT = ub + 16384000;
  unsigned short* woT = wqkvT + 786432;
  unsigned short* w1T = woT + 262144;
  unsigned short* w2T = w1T + 1048576;

  hipMemsetAsync(out, 0, (size_t)BSD * sizeof(float), stream);

  // fused: local_agg+gather+LN1 (256) | weight cast (768) | gating (800)
  front_kernel<<<1824, 256, 0, stream>>>(
      items, adj, emb, agg_a, alias, hbuf, xb, ln1g, ln1b,
      ids, Wg, Wn, eps, gates,
      Wq, Wk, Wv, Wo, W1, W2, wqkvT, woT, w1T, w2T);
  // fused QKV projection + causal MHA -> obuf
  qkv_attn<<<K_ * B_ * H_, 256, 0, stream>>>(xb, wqkvT, obuf);
  // fused O-proj + residual + LN2 + FFN1 + FFN2 + gated combine -> out
  tail_fused<<<K_ * B_, 256, 0, stream>>>(obuf, woT, w1T, w2T, hbuf, gates,
                                          ln2g, ln2b, out);
}